// Round 1
// baseline (1436.642 us; speedup 1.0000x reference)
//
#include <hip/hip_runtime.h>
#include <hip/hip_fp16.h>

#define B_ 256
#define T_ 512
#define I_ 156
#define H_ 128
#define L_ 32
#define G_ 512  // 4*H

typedef _Float16 half_t;
typedef _Float16 h2_t __attribute__((ext_vector_type(2)));

union U8 { uint4 u; h2_t h2[4]; };

__device__ __forceinline__ float fdot2(h2_t a, h2_t b, float c) {
#if __has_builtin(__builtin_amdgcn_fdot2)
  return __builtin_amdgcn_fdot2(a, b, c, false);
#else
  return c + (float)a[0] * (float)b[0] + (float)a[1] * (float)b[1];
#endif
}

__device__ __forceinline__ h2_t pk2(float a, float b) {
  h2_t r; r[0] = (half_t)a; r[1] = (half_t)b; return r;
}

__device__ __forceinline__ float sigf(float x) { return 1.0f / (1.0f + __expf(-x)); }
__device__ __forceinline__ float tanhf_(float x) {
  x = fminf(fmaxf(x, -20.f), 20.f);
  float e = __expf(2.f * x);
  return (e - 1.f) / (e + 1.f);
}

// ---------------- encoder: 1 block per batch element ----------------
__global__ __launch_bounds__(512, 2) void enc_kernel(
    const float* __restrict__ motion, const float* __restrict__ eps,
    const float* __restrict__ Wih, const float* __restrict__ Whh,
    const float* __restrict__ bv,
    const float* __restrict__ muW, const float* __restrict__ mub,
    const float* __restrict__ varW, const float* __restrict__ varb,
    const float* __restrict__ fcW, const float* __restrict__ fcb,
    float* __restrict__ dout, float* __restrict__ dh0,
    float* __restrict__ accums)
{
  const int j = threadIdx.x;   // gate row 0..511
  const int b = blockIdx.x;    // batch element

  __shared__ U8 xs[20];        // x_t as 80 half2 (156 + pad)
  __shared__ U8 hs[16];        // h   as 64 half2 (128)
  __shared__ float gl[G_];
  __shared__ float hf[H_];
  __shared__ float mulv[64];
  __shared__ float zs[L_];

  // per-thread weight rows, packed f16 (stay in VGPRs)
  h2_t wih[80];
  h2_t whh[64];
  {
    const float2* r = (const float2*)(Wih + j * I_);
#pragma unroll
    for (int k = 0; k < 78; ++k) { float2 w = r[k]; wih[k] = pk2(w.x, w.y); }
    wih[78] = pk2(0.f, 0.f); wih[79] = pk2(0.f, 0.f);
    const float2* r2 = (const float2*)(Whh + j * H_);
#pragma unroll
    for (int k = 0; k < 64; ++k) { float2 w = r2[k]; whh[k] = pk2(w.x, w.y); }
  }
  const float bj = bv[j];

  float creg = 0.f, hreg = 0.f;
  if (j < 64) { ((h2_t*)hs)[j] = pk2(0.f, 0.f); }  // h0 = 0

  const float2* mrow = (const float2*)(motion + (size_t)b * T_ * I_);

  for (int t = 0; t < T_; ++t) {
    // stage x_t into LDS as f16
    if (j < 80) {
      h2_t v = pk2(0.f, 0.f);
      if (j < 78) { float2 m = mrow[t * 78 + j]; v = pk2(m.x, m.y); }
      ((h2_t*)xs)[j] = v;
    }
    __syncthreads();
    // gate j = b_j + Wih[j,:]·x + Whh[j,:]·h   (f16 dot2, f32 accum)
    float acc = bj;
#pragma unroll
    for (int c = 0; c < 20; ++c) {
      U8 xv = xs[c];
      acc = fdot2(wih[4*c+0], xv.h2[0], acc);
      acc = fdot2(wih[4*c+1], xv.h2[1], acc);
      acc = fdot2(wih[4*c+2], xv.h2[2], acc);
      acc = fdot2(wih[4*c+3], xv.h2[3], acc);
    }
#pragma unroll
    for (int c = 0; c < 16; ++c) {
      U8 hv = hs[c];
      acc = fdot2(whh[4*c+0], hv.h2[0], acc);
      acc = fdot2(whh[4*c+1], hv.h2[1], acc);
      acc = fdot2(whh[4*c+2], hv.h2[2], acc);
      acc = fdot2(whh[4*c+3], hv.h2[3], acc);
    }
    gl[j] = acc;
    __syncthreads();
    // cell update (PyTorch gate order i,f,g,o)
    if (j < H_) {
      float ig = gl[j], fg = gl[j + H_], gg = gl[j + 2*H_], og = gl[j + 3*H_];
      creg = sigf(fg) * creg + sigf(ig) * tanhf_(gg);
      hreg = sigf(og) * tanhf_(creg);
      ((half_t*)hs)[j] = (half_t)hreg;
    }
    __syncthreads();
  }

  // final hidden (f32) for mu/logvar
  if (j < H_) hf[j] = hreg;
  __syncthreads();

  if (j < 64) {
    const float* wr = (j < L_) ? (muW + j * H_) : (varW + (j - L_) * H_);
    float a = (j < L_) ? mub[j] : varb[j - L_];
#pragma unroll 8
    for (int k = 0; k < H_; ++k) a += wr[k] * hf[k];
    mulv[j] = a;
    if (j < L_) dout[(size_t)B_*T_*I_ + b * L_ + j] = a;
    else        dout[(size_t)B_*T_*I_ + B_*L_ + b * L_ + (j - L_)] = a;
  }
  __syncthreads();

  if (j < L_) {
    float mu = mulv[j], lv = mulv[j + L_];
    float z = mu + eps[b * L_ + j] * __expf(0.5f * lv);
    zs[j] = z;
    float kt = 1.f + lv - mu * mu - __expf(lv);
#pragma unroll
    for (int off = 16; off > 0; off >>= 1) kt += __shfl_down(kt, off, 64);
    if (j == 0) atomicAdd(&accums[1], kt);   // raw sum; -0.5 applied in finisher
  }
  __syncthreads();

  if (j < H_) {
    const float* wr = fcW + j * L_;
    float a = fcb[j];
#pragma unroll
    for (int l = 0; l < L_; ++l) a += wr[l] * zs[l];
    dh0[b * H_ + j] = a;
  }
}

// ---------------- decoder: 1 block per batch element ----------------
__global__ __launch_bounds__(512, 2) void dec_kernel(
    const float* __restrict__ motion,
    const float* __restrict__ Wih, const float* __restrict__ Whh,
    const float* __restrict__ bv,
    const float* __restrict__ oW, const float* __restrict__ ob,
    const float* __restrict__ dh0,
    float* __restrict__ dout, float* __restrict__ accums)
{
  const int j = threadIdx.x;
  const int b = blockIdx.x;

  __shared__ U8 hs[16];
  __shared__ float gl[G_];
  __shared__ float red[8];

  // folded recurrent weights: (dec_Wih + dec_Whh) row j
  h2_t wd[64];
  {
    const float2* r1 = (const float2*)(Wih + j * H_);
    const float2* r2 = (const float2*)(Whh + j * H_);
#pragma unroll
    for (int k = 0; k < 64; ++k) {
      float2 a = r1[k], c = r2[k];
      wd[k] = pk2(a.x + c.x, a.y + c.y);
    }
  }
  const float bj = bv[j];

  h2_t wo[64];
  float obj = 0.f;
  if (j < I_) {
    const float2* r = (const float2*)(oW + j * H_);
#pragma unroll
    for (int k = 0; k < 64; ++k) { float2 w = r[k]; wo[k] = pk2(w.x, w.y); }
    obj = ob[j];
  } else {
#pragma unroll
    for (int k = 0; k < 64; ++k) wo[k] = pk2(0.f, 0.f);
  }

  float creg = 0.f, hreg = 0.f;
  if (j < H_) {
    hreg = dh0[b * H_ + j];
    ((half_t*)hs)[j] = (half_t)hreg;
  }
  __syncthreads();

  const float* mrow = motion + (size_t)b * T_ * I_;
  float* rrow = dout + (size_t)b * T_ * I_;
  float rl = 0.f;

  for (int t = 0; t < T_; ++t) {
    // gates from h_{t-1}
    float acc = bj;
#pragma unroll
    for (int c = 0; c < 16; ++c) {
      U8 hv = hs[c];
      acc = fdot2(wd[4*c+0], hv.h2[0], acc);
      acc = fdot2(wd[4*c+1], hv.h2[1], acc);
      acc = fdot2(wd[4*c+2], hv.h2[2], acc);
      acc = fdot2(wd[4*c+3], hv.h2[3], acc);
    }
    gl[j] = acc;
    __syncthreads();
    if (j < H_) {
      float ig = gl[j], fg = gl[j + H_], gg = gl[j + 2*H_], og = gl[j + 3*H_];
      creg = sigf(fg) * creg + sigf(ig) * tanhf_(gg);
      hreg = sigf(og) * tanhf_(creg);
      ((half_t*)hs)[j] = (half_t)hreg;
    }
    __syncthreads();
    // output projection of h_t (post-update) + fused rec-loss
    if (j < I_) {
      float r = obj;
#pragma unroll
      for (int c = 0; c < 16; ++c) {
        U8 hv = hs[c];
        r = fdot2(wo[4*c+0], hv.h2[0], r);
        r = fdot2(wo[4*c+1], hv.h2[1], r);
        r = fdot2(wo[4*c+2], hv.h2[2], r);
        r = fdot2(wo[4*c+3], hv.h2[3], r);
      }
      rrow[t * I_ + j] = r;
      float d = r - mrow[t * I_ + j];
      rl += d * d;
    }
    // no barrier needed here: next write to hs is after next sync
  }

  // block reduction of squared error
  float v = rl;
#pragma unroll
  for (int off = 32; off > 0; off >>= 1) v += __shfl_down(v, off, 64);
  if ((j & 63) == 0) red[j >> 6] = v;
  __syncthreads();
  if (j == 0) {
    float s = 0.f;
#pragma unroll
    for (int w = 0; w < 8; ++w) s += red[w];
    atomicAdd(&accums[0], s);
  }
}

__global__ void init_kernel(float* accums) {
  if (threadIdx.x < 2) accums[threadIdx.x] = 0.f;
}

__global__ void fin_kernel(const float* __restrict__ accums, float* __restrict__ dout) {
  if (threadIdx.x == 0) {
    float rec = accums[0] / (float)((size_t)B_ * T_ * I_);
    float kl = -0.5f * accums[1];
    dout[(size_t)B_*T_*I_ + 2 * B_ * L_] = rec + kl;
  }
}

extern "C" void kernel_launch(void* const* d_in, const int* in_sizes, int n_in,
                              void* d_out, int out_size, void* d_ws, size_t ws_size,
                              hipStream_t stream) {
  const float* motion = (const float*)d_in[0];
  const float* eps    = (const float*)d_in[1];
  const float* eWih   = (const float*)d_in[2];
  const float* eWhh   = (const float*)d_in[3];
  const float* eb     = (const float*)d_in[4];
  const float* muW    = (const float*)d_in[5];
  const float* mub    = (const float*)d_in[6];
  const float* varW   = (const float*)d_in[7];
  const float* varb   = (const float*)d_in[8];
  const float* fcW    = (const float*)d_in[9];
  const float* fcb    = (const float*)d_in[10];
  const float* dWih   = (const float*)d_in[11];
  const float* dWhh   = (const float*)d_in[12];
  const float* db     = (const float*)d_in[13];
  const float* oW     = (const float*)d_in[14];
  const float* obv    = (const float*)d_in[15];
  float* out = (float*)d_out;
  float* accums = (float*)d_ws;        // [0]=rec sum, [1]=kl raw sum
  float* dh0    = (float*)d_ws + 16;   // 256*128 f32

  hipLaunchKernelGGL(init_kernel, dim3(1), dim3(64), 0, stream, accums);
  hipLaunchKernelGGL(enc_kernel, dim3(B_), dim3(512), 0, stream,
                     motion, eps, eWih, eWhh, eb, muW, mub, varW, varb, fcW, fcb,
                     out, dh0, accums);
  hipLaunchKernelGGL(dec_kernel, dim3(B_), dim3(512), 0, stream,
                     motion, dWih, dWhh, db, oW, obv, dh0, out, accums);
  hipLaunchKernelGGL(fin_kernel, dim3(1), dim3(64), 0, stream, accums, out);
}

// Round 2
// 1161.751 us; speedup vs baseline: 1.2366x; 1.2366x over previous
//
#include <hip/hip_runtime.h>
#include <hip/hip_fp16.h>

#define B_ 256
#define T_ 512
#define I_ 156
#define H_ 128
#define L_ 32
#define G_ 512  // 4*H

typedef _Float16 half_t;
typedef _Float16 h2_t __attribute__((ext_vector_type(2)));

union U8 { uint4 u; h2_t h2[4]; };

__device__ __forceinline__ float fdot2(h2_t a, h2_t b, float c) {
#if __has_builtin(__builtin_amdgcn_fdot2)
  return __builtin_amdgcn_fdot2(a, b, c, false);
#else
  return c + (float)a[0] * (float)b[0] + (float)a[1] * (float)b[1];
#endif
}

__device__ __forceinline__ h2_t pk2(float a, float b) {
  h2_t r; r[0] = (half_t)a; r[1] = (half_t)b; return r;
}

__device__ __forceinline__ float sigf(float x) { return 1.0f / (1.0f + __expf(-x)); }
__device__ __forceinline__ float tanhf_(float x) {
  x = fminf(fmaxf(x, -20.f), 20.f);
  float e = __expf(2.f * x);
  return (e - 1.f) / (e + 1.f);
}

// ---------------- encoder: 1 block (1024 thr) per batch element ----------------
// Threads are split into two halves; each gate row j's dot product is computed
// by thread (0,j) and (1,j), 72 fdot2 each, combined in the cell phase.
__global__ __launch_bounds__(1024, 4) void enc_kernel(
    const float* __restrict__ motion, const float* __restrict__ eps,
    const float* __restrict__ Wih, const float* __restrict__ Whh,
    const float* __restrict__ bv,
    const float* __restrict__ muW, const float* __restrict__ mub,
    const float* __restrict__ varW, const float* __restrict__ varb,
    const float* __restrict__ fcW, const float* __restrict__ fcb,
    float* __restrict__ dout, float* __restrict__ dh0,
    float* __restrict__ accums)
{
  const int tid  = threadIdx.x;
  const int part = tid >> 9;     // 0 or 1
  const int j    = tid & 511;    // gate row
  const int b    = blockIdx.x;

  __shared__ h2_t xs[2][80];     // x_t (156 f16 + pad to 160), double-buffered
  __shared__ h2_t hs[64];        // h as 128 f16
  __shared__ float gl2[2][G_];   // partial gate sums
  __shared__ float hf[H_];
  __shared__ float mulv[64];
  __shared__ float zs[L_];

  // per-thread packed-f16 weight slices (stay in VGPRs)
  h2_t wih[40];                  // columns [part*80, part*80+80) of Wih row j
  h2_t whh[32];                  // columns [part*64, part*64+64) of Whh row j
  {
    const int cbase = part * 80;
    const float* wr = Wih + (size_t)j * I_;
#pragma unroll
    for (int k = 0; k < 40; ++k) {
      int c0 = cbase + 2 * k;
      float a = (c0     < I_) ? wr[c0]     : 0.f;
      float c = (c0 + 1 < I_) ? wr[c0 + 1] : 0.f;
      wih[k] = pk2(a, c);
    }
    const float2* r2 = (const float2*)(Whh + (size_t)j * H_ + part * 64);
#pragma unroll
    for (int k = 0; k < 32; ++k) { float2 w = r2[k]; whh[k] = pk2(w.x, w.y); }
  }

  // cell-phase biases (threads 0..127)
  float cb0 = 0.f, cb1 = 0.f, cb2 = 0.f, cb3 = 0.f;
  if (tid < H_) {
    cb0 = bv[tid]; cb1 = bv[tid + H_]; cb2 = bv[tid + 2*H_]; cb3 = bv[tid + 3*H_];
  }

  float creg = 0.f, hreg = 0.f;
  if (tid < 64) hs[tid] = pk2(0.f, 0.f);
  if (tid < 4)  xs[tid >> 1][78 + (tid & 1)] = pk2(0.f, 0.f);  // static zero pad

  const float2* mrow = (const float2*)(motion + (size_t)b * T_ * I_);
  const bool loader = (part == 1) && (j < 78);
  if (loader) { float2 m = mrow[j]; xs[0][j] = pk2(m.x, m.y); }
  __syncthreads();

  int cur = 0;
  float2 xreg;
  for (int t = 0; t < T_; ++t) {
    if (loader && t + 1 < T_) xreg = mrow[(t + 1) * 78 + j];

    float a0 = 0.f, a1 = 0.f, a2 = 0.f, a3 = 0.f;
    const U8* xv = (const U8*)&xs[cur][part * 40];
#pragma unroll
    for (int c = 0; c < 10; ++c) {
      U8 v = xv[c];
      a0 = fdot2(wih[4*c+0], v.h2[0], a0);
      a1 = fdot2(wih[4*c+1], v.h2[1], a1);
      a2 = fdot2(wih[4*c+2], v.h2[2], a2);
      a3 = fdot2(wih[4*c+3], v.h2[3], a3);
    }
    const U8* hv = (const U8*)&hs[part * 32];
#pragma unroll
    for (int c = 0; c < 8; ++c) {
      U8 v = hv[c];
      a0 = fdot2(whh[4*c+0], v.h2[0], a0);
      a1 = fdot2(whh[4*c+1], v.h2[1], a1);
      a2 = fdot2(whh[4*c+2], v.h2[2], a2);
      a3 = fdot2(whh[4*c+3], v.h2[3], a3);
    }
    gl2[part][j] = (a0 + a1) + (a2 + a3);
    if (loader && t + 1 < T_) xs[cur ^ 1][j] = pk2(xreg.x, xreg.y);
    __syncthreads();

    if (tid < H_) {
      float ig = gl2[0][tid]         + gl2[1][tid]         + cb0;
      float fg = gl2[0][tid +   H_]  + gl2[1][tid +   H_]  + cb1;
      float gg = gl2[0][tid + 2*H_]  + gl2[1][tid + 2*H_]  + cb2;
      float og = gl2[0][tid + 3*H_]  + gl2[1][tid + 3*H_]  + cb3;
      creg = sigf(fg) * creg + sigf(ig) * tanhf_(gg);
      hreg = sigf(og) * tanhf_(creg);
      ((half_t*)hs)[tid] = (half_t)hreg;
    }
    __syncthreads();
    cur ^= 1;
  }

  // ---- tail: mu/logvar, z, KL, dh0 ----
  if (tid < H_) hf[tid] = hreg;
  __syncthreads();

  if (tid < 64) {
    const float* wr = (tid < L_) ? (muW + tid * H_) : (varW + (tid - L_) * H_);
    float a = (tid < L_) ? mub[tid] : varb[tid - L_];
#pragma unroll 8
    for (int k = 0; k < H_; ++k) a += wr[k] * hf[k];
    mulv[tid] = a;
    if (tid < L_) dout[(size_t)B_*T_*I_ + b * L_ + tid] = a;
    else          dout[(size_t)B_*T_*I_ + B_*L_ + b * L_ + (tid - L_)] = a;
  }
  __syncthreads();

  if (tid < L_) {
    float mu = mulv[tid], lv = mulv[tid + L_];
    float z = mu + eps[b * L_ + tid] * __expf(0.5f * lv);
    zs[tid] = z;
    float kt = 1.f + lv - mu * mu - __expf(lv);
#pragma unroll
    for (int off = 16; off > 0; off >>= 1) kt += __shfl_down(kt, off, 64);
    if (tid == 0) atomicAdd(&accums[1], kt);
  }
  __syncthreads();

  if (tid < H_) {
    const float* wr = fcW + tid * L_;
    float a = fcb[tid];
#pragma unroll
    for (int l = 0; l < L_; ++l) a += wr[l] * zs[l];
    dh0[b * H_ + tid] = a;
  }
}

// ---------------- decoder: 1 block (1024 thr) per batch element ----------------
// half0 (512 thr): full gate rows (folded Wih+Whh).  half1 (156 thr): output
// projection of the SAME h_t, overlapped in the same phase (recon[t-1]).
__global__ __launch_bounds__(1024, 4) void dec_kernel(
    const float* __restrict__ motion,
    const float* __restrict__ Wih, const float* __restrict__ Whh,
    const float* __restrict__ bv,
    const float* __restrict__ oW, const float* __restrict__ ob,
    const float* __restrict__ dh0,
    float* __restrict__ dout, float* __restrict__ accums)
{
  const int tid  = threadIdx.x;
  const int part = tid >> 9;
  const int j    = tid & 511;
  const int b    = blockIdx.x;

  __shared__ h2_t hs[64];
  __shared__ float gl[G_];
  __shared__ float red[16];

  h2_t wv[64];
  float bj = 0.f;
  if (part == 0) {
    const float2* r1 = (const float2*)(Wih + (size_t)j * H_);
    const float2* r2 = (const float2*)(Whh + (size_t)j * H_);
#pragma unroll
    for (int k = 0; k < 64; ++k) {
      float2 a = r1[k], c = r2[k];
      wv[k] = pk2(a.x + c.x, a.y + c.y);
    }
    bj = bv[j];
  } else if (j < I_) {
    const float2* r = (const float2*)(oW + (size_t)j * H_);
#pragma unroll
    for (int k = 0; k < 64; ++k) { float2 w = r[k]; wv[k] = pk2(w.x, w.y); }
    bj = ob[j];
  }

  float creg = 0.f, hreg = 0.f;
  if (tid < H_) {
    hreg = dh0[b * H_ + tid];
    ((half_t*)hs)[tid] = (half_t)hreg;
  }
  __syncthreads();

  const float* mr = motion + (size_t)b * T_ * I_;
  float* rr = dout + (size_t)b * T_ * I_;
  float rl = 0.f;

  for (int t = 0; t < T_; ++t) {
    if (part == 0) {
      float a0 = 0.f, a1 = 0.f, a2 = 0.f, a3 = 0.f;
      const U8* hv = (const U8*)hs;
#pragma unroll
      for (int c = 0; c < 16; ++c) {
        U8 v = hv[c];
        a0 = fdot2(wv[4*c+0], v.h2[0], a0);
        a1 = fdot2(wv[4*c+1], v.h2[1], a1);
        a2 = fdot2(wv[4*c+2], v.h2[2], a2);
        a3 = fdot2(wv[4*c+3], v.h2[3], a3);
      }
      gl[j] = bj + (a0 + a1) + (a2 + a3);
    } else if (j < I_ && t > 0) {
      float a0 = 0.f, a1 = 0.f, a2 = 0.f, a3 = 0.f;
      const U8* hv = (const U8*)hs;
#pragma unroll
      for (int c = 0; c < 16; ++c) {
        U8 v = hv[c];
        a0 = fdot2(wv[4*c+0], v.h2[0], a0);
        a1 = fdot2(wv[4*c+1], v.h2[1], a1);
        a2 = fdot2(wv[4*c+2], v.h2[2], a2);
        a3 = fdot2(wv[4*c+3], v.h2[3], a3);
      }
      float r = bj + (a0 + a1) + (a2 + a3);
      rr[(t - 1) * I_ + j] = r;
      float d = r - mr[(t - 1) * I_ + j];
      rl += d * d;
    }
    __syncthreads();

    if (tid < H_) {
      float ig = gl[tid], fg = gl[tid + H_], gg = gl[tid + 2*H_], og = gl[tid + 3*H_];
      creg = sigf(fg) * creg + sigf(ig) * tanhf_(gg);
      hreg = sigf(og) * tanhf_(creg);
      ((half_t*)hs)[tid] = (half_t)hreg;
    }
    __syncthreads();
  }

  // epilogue projection: recon[511] = proj(h_512)
  if (part == 1 && j < I_) {
    float a0 = 0.f, a1 = 0.f, a2 = 0.f, a3 = 0.f;
    const U8* hv = (const U8*)hs;
#pragma unroll
    for (int c = 0; c < 16; ++c) {
      U8 v = hv[c];
      a0 = fdot2(wv[4*c+0], v.h2[0], a0);
      a1 = fdot2(wv[4*c+1], v.h2[1], a1);
      a2 = fdot2(wv[4*c+2], v.h2[2], a2);
      a3 = fdot2(wv[4*c+3], v.h2[3], a3);
    }
    float r = bj + (a0 + a1) + (a2 + a3);
    rr[511 * I_ + j] = r;
    float d = r - mr[511 * I_ + j];
    rl += d * d;
  }

  // block reduction of squared error
  float v = rl;
#pragma unroll
  for (int off = 32; off > 0; off >>= 1) v += __shfl_down(v, off, 64);
  if ((tid & 63) == 0) red[tid >> 6] = v;
  __syncthreads();
  if (tid == 0) {
    float s = 0.f;
#pragma unroll
    for (int w = 0; w < 16; ++w) s += red[w];
    atomicAdd(&accums[0], s);
  }
}

__global__ void init_kernel(float* accums) {
  if (threadIdx.x < 2) accums[threadIdx.x] = 0.f;
}

__global__ void fin_kernel(const float* __restrict__ accums, float* __restrict__ dout) {
  if (threadIdx.x == 0) {
    float rec = accums[0] / (float)((size_t)B_ * T_ * I_);
    float kl = -0.5f * accums[1];
    dout[(size_t)B_*T_*I_ + 2 * B_ * L_] = rec + kl;
  }
}

extern "C" void kernel_launch(void* const* d_in, const int* in_sizes, int n_in,
                              void* d_out, int out_size, void* d_ws, size_t ws_size,
                              hipStream_t stream) {
  const float* motion = (const float*)d_in[0];
  const float* eps    = (const float*)d_in[1];
  const float* eWih   = (const float*)d_in[2];
  const float* eWhh   = (const float*)d_in[3];
  const float* eb     = (const float*)d_in[4];
  const float* muW    = (const float*)d_in[5];
  const float* mub    = (const float*)d_in[6];
  const float* varW   = (const float*)d_in[7];
  const float* varb   = (const float*)d_in[8];
  const float* fcW    = (const float*)d_in[9];
  const float* fcb    = (const float*)d_in[10];
  const float* dWih   = (const float*)d_in[11];
  const float* dWhh   = (const float*)d_in[12];
  const float* db     = (const float*)d_in[13];
  const float* oW     = (const float*)d_in[14];
  const float* obv    = (const float*)d_in[15];
  float* out = (float*)d_out;
  float* accums = (float*)d_ws;        // [0]=rec sum, [1]=kl raw sum
  float* dh0    = (float*)d_ws + 16;   // 256*128 f32

  hipLaunchKernelGGL(init_kernel, dim3(1), dim3(64), 0, stream, accums);
  hipLaunchKernelGGL(enc_kernel, dim3(B_), dim3(1024), 0, stream,
                     motion, eps, eWih, eWhh, eb, muW, mub, varW, varb, fcW, fcb,
                     out, dh0, accums);
  hipLaunchKernelGGL(dec_kernel, dim3(B_), dim3(1024), 0, stream,
                     motion, dWih, dWhh, db, oW, obv, dh0, out, accums);
  hipLaunchKernelGGL(fin_kernel, dim3(1), dim3(64), 0, stream, accums, out);
}

// Round 4
// 1154.758 us; speedup vs baseline: 1.2441x; 1.0061x over previous
//
#include <hip/hip_runtime.h>
#include <hip/hip_fp16.h>

#define B_ 256
#define T_ 512
#define I_ 156
#define H_ 128
#define L_ 32
#define G_ 512  // 4*H

typedef _Float16 half_t;
typedef _Float16 h2_t __attribute__((ext_vector_type(2)));

union U8 { uint4 u; h2_t h2[4]; };

__device__ __forceinline__ float fdot2(h2_t a, h2_t b, float c) {
#if __has_builtin(__builtin_amdgcn_fdot2)
  return __builtin_amdgcn_fdot2(a, b, c, false);
#else
  return c + (float)a[0] * (float)b[0] + (float)a[1] * (float)b[1];
#endif
}

__device__ __forceinline__ h2_t pk2(float a, float b) {
  h2_t r; r[0] = (half_t)a; r[1] = (half_t)b; return r;
}

__device__ __forceinline__ float sigf(float x) { return 1.0f / (1.0f + __expf(-x)); }
__device__ __forceinline__ float tanhf_(float x) {
  x = fminf(fmaxf(x, -20.f), 20.f);
  float e = __expf(2.f * x);
  return (e - 1.f) / (e + 1.f);
}

// ---------------- encoder: 1 block (1024 thr) per batch element ----------------
// Each gate row j's dot product is split across threads (0,j) and (1,j).
// amdgpu_waves_per_eu(4,4) => 128 VGPRs/thread so the ~72 h2 weight regs stay
// in registers (R1 spilled 40 regs to scratch at the compiler-chosen 64 VGPRs).
__global__ __launch_bounds__(1024)
__attribute__((amdgpu_waves_per_eu(4, 4)))
void enc_kernel(
    const float* __restrict__ motion, const float* __restrict__ eps,
    const float* __restrict__ Wih, const float* __restrict__ Whh,
    const float* __restrict__ bv,
    const float* __restrict__ muW, const float* __restrict__ mub,
    const float* __restrict__ varW, const float* __restrict__ varb,
    const float* __restrict__ fcW, const float* __restrict__ fcb,
    float* __restrict__ dout, float* __restrict__ dh0,
    float* __restrict__ accums)
{
  const int tid  = threadIdx.x;
  const int part = tid >> 9;     // 0 or 1
  const int j    = tid & 511;    // gate row
  const int b    = blockIdx.x;

  __shared__ h2_t xs[2][80];     // x_t (156 f16 + pad to 160), double-buffered
  __shared__ h2_t hs[64];        // h as 128 f16
  __shared__ float gl2[2][G_];   // partial gate sums
  __shared__ float hf[H_];
  __shared__ float mulv[64];
  __shared__ float zs[L_];

  // per-thread packed-f16 weight slices (must stay in VGPRs)
  h2_t wih[40];                  // columns [part*80, part*80+80) of Wih row j
  h2_t whh[32];                  // columns [part*64, part*64+64) of Whh row j
  {
    const int cbase = part * 80;
    const float* wr = Wih + (size_t)j * I_;
#pragma unroll
    for (int k = 0; k < 40; ++k) {
      int c0 = cbase + 2 * k;
      float a = (c0     < I_) ? wr[c0]     : 0.f;
      float c = (c0 + 1 < I_) ? wr[c0 + 1] : 0.f;
      wih[k] = pk2(a, c);
    }
    const float2* r2 = (const float2*)(Whh + (size_t)j * H_ + part * 64);
#pragma unroll
    for (int k = 0; k < 32; ++k) { float2 w = r2[k]; whh[k] = pk2(w.x, w.y); }
  }

  // cell-phase biases (threads 0..127)
  float cb0 = 0.f, cb1 = 0.f, cb2 = 0.f, cb3 = 0.f;
  if (tid < H_) {
    cb0 = bv[tid]; cb1 = bv[tid + H_]; cb2 = bv[tid + 2*H_]; cb3 = bv[tid + 3*H_];
  }

  float creg = 0.f, hreg = 0.f;
  if (tid < 64) hs[tid] = pk2(0.f, 0.f);
  if (tid < 4)  xs[tid >> 1][78 + (tid & 1)] = pk2(0.f, 0.f);  // static zero pad

  const float2* mrow = (const float2*)(motion + (size_t)b * T_ * I_);
  const bool loader = (part == 1) && (j < 78);
  if (loader) { float2 m = mrow[j]; xs[0][j] = pk2(m.x, m.y); }
  __syncthreads();

  int cur = 0;
  float2 xreg;
  for (int t = 0; t < T_; ++t) {
    if (loader && t + 1 < T_) xreg = mrow[(t + 1) * 78 + j];

    float a0 = 0.f, a1 = 0.f, a2 = 0.f, a3 = 0.f;
    const U8* xv = (const U8*)&xs[cur][part * 40];
#pragma unroll
    for (int c = 0; c < 10; ++c) {
      U8 v = xv[c];
      a0 = fdot2(wih[4*c+0], v.h2[0], a0);
      a1 = fdot2(wih[4*c+1], v.h2[1], a1);
      a2 = fdot2(wih[4*c+2], v.h2[2], a2);
      a3 = fdot2(wih[4*c+3], v.h2[3], a3);
    }
    const U8* hv = (const U8*)&hs[part * 32];
#pragma unroll
    for (int c = 0; c < 8; ++c) {
      U8 v = hv[c];
      a0 = fdot2(whh[4*c+0], v.h2[0], a0);
      a1 = fdot2(whh[4*c+1], v.h2[1], a1);
      a2 = fdot2(whh[4*c+2], v.h2[2], a2);
      a3 = fdot2(whh[4*c+3], v.h2[3], a3);
    }
    gl2[part][j] = (a0 + a1) + (a2 + a3);
    if (loader && t + 1 < T_) xs[cur ^ 1][j] = pk2(xreg.x, xreg.y);
    __syncthreads();

    if (tid < H_) {
      float ig = gl2[0][tid]         + gl2[1][tid]         + cb0;
      float fg = gl2[0][tid +   H_]  + gl2[1][tid +   H_]  + cb1;
      float gg = gl2[0][tid + 2*H_]  + gl2[1][tid + 2*H_]  + cb2;
      float og = gl2[0][tid + 3*H_]  + gl2[1][tid + 3*H_]  + cb3;
      creg = sigf(fg) * creg + sigf(ig) * tanhf_(gg);
      hreg = sigf(og) * tanhf_(creg);
      ((half_t*)hs)[tid] = (half_t)hreg;
    }
    __syncthreads();
    cur ^= 1;
  }

  // ---- tail: mu/logvar, z, KL, dh0 ----
  if (tid < H_) hf[tid] = hreg;
  __syncthreads();

  if (tid < 64) {
    const float* wr = (tid < L_) ? (muW + tid * H_) : (varW + (tid - L_) * H_);
    float a = (tid < L_) ? mub[tid] : varb[tid - L_];
#pragma unroll 8
    for (int k = 0; k < H_; ++k) a += wr[k] * hf[k];
    mulv[tid] = a;
    if (tid < L_) dout[(size_t)B_*T_*I_ + b * L_ + tid] = a;
    else          dout[(size_t)B_*T_*I_ + B_*L_ + b * L_ + (tid - L_)] = a;
  }
  __syncthreads();

  if (tid < L_) {
    float mu = mulv[tid], lv = mulv[tid + L_];
    float z = mu + eps[b * L_ + tid] * __expf(0.5f * lv);
    zs[tid] = z;
    float kt = 1.f + lv - mu * mu - __expf(lv);
#pragma unroll
    for (int off = 16; off > 0; off >>= 1) kt += __shfl_down(kt, off, 64);
    if (tid == 0) atomicAdd(&accums[1], kt);
  }
  __syncthreads();

  if (tid < H_) {
    const float* wr = fcW + tid * L_;
    float a = fcb[tid];
#pragma unroll
    for (int l = 0; l < L_; ++l) a += wr[l] * zs[l];
    dh0[b * H_ + tid] = a;
  }
}

// ---------------- decoder: 1 block (1024 thr) per batch element ----------------
// half0 (512 thr): full gate rows (folded Wih+Whh).  half1 (156 thr): output
// projection of the SAME h_t, overlapped in the same phase (recon[t-1]).
__global__ __launch_bounds__(1024)
__attribute__((amdgpu_waves_per_eu(4, 4)))
void dec_kernel(
    const float* __restrict__ motion,
    const float* __restrict__ Wih, const float* __restrict__ Whh,
    const float* __restrict__ bv,
    const float* __restrict__ oW, const float* __restrict__ ob,
    const float* __restrict__ dh0,
    float* __restrict__ dout, float* __restrict__ accums)
{
  const int tid  = threadIdx.x;
  const int part = tid >> 9;
  const int j    = tid & 511;
  const int b    = blockIdx.x;

  __shared__ h2_t hs[64];
  __shared__ float gl[G_];
  __shared__ float red[16];

  h2_t wv[64];
  float bj = 0.f;
  if (part == 0) {
    const float2* r1 = (const float2*)(Wih + (size_t)j * H_);
    const float2* r2 = (const float2*)(Whh + (size_t)j * H_);
#pragma unroll
    for (int k = 0; k < 64; ++k) {
      float2 a = r1[k], c = r2[k];
      wv[k] = pk2(a.x + c.x, a.y + c.y);
    }
    bj = bv[j];
  } else if (j < I_) {
    const float2* r = (const float2*)(oW + (size_t)j * H_);
#pragma unroll
    for (int k = 0; k < 64; ++k) { float2 w = r[k]; wv[k] = pk2(w.x, w.y); }
    bj = ob[j];
  }

  float creg = 0.f, hreg = 0.f;
  if (tid < H_) {
    hreg = dh0[b * H_ + tid];
    ((half_t*)hs)[tid] = (half_t)hreg;
  }
  __syncthreads();

  const float* mr = motion + (size_t)b * T_ * I_;
  float* rr = dout + (size_t)b * T_ * I_;
  float rl = 0.f;

  for (int t = 0; t < T_; ++t) {
    if (part == 0) {
      float a0 = 0.f, a1 = 0.f, a2 = 0.f, a3 = 0.f;
      const U8* hv = (const U8*)hs;
#pragma unroll
      for (int c = 0; c < 16; ++c) {
        U8 v = hv[c];
        a0 = fdot2(wv[4*c+0], v.h2[0], a0);
        a1 = fdot2(wv[4*c+1], v.h2[1], a1);
        a2 = fdot2(wv[4*c+2], v.h2[2], a2);
        a3 = fdot2(wv[4*c+3], v.h2[3], a3);
      }
      gl[j] = bj + (a0 + a1) + (a2 + a3);
    } else if (j < I_ && t > 0) {
      float a0 = 0.f, a1 = 0.f, a2 = 0.f, a3 = 0.f;
      const U8* hv = (const U8*)hs;
#pragma unroll
      for (int c = 0; c < 16; ++c) {
        U8 v = hv[c];
        a0 = fdot2(wv[4*c+0], v.h2[0], a0);
        a1 = fdot2(wv[4*c+1], v.h2[1], a1);
        a2 = fdot2(wv[4*c+2], v.h2[2], a2);
        a3 = fdot2(wv[4*c+3], v.h2[3], a3);
      }
      float r = bj + (a0 + a1) + (a2 + a3);
      rr[(t - 1) * I_ + j] = r;
      float d = r - mr[(t - 1) * I_ + j];
      rl += d * d;
    }
    __syncthreads();

    if (tid < H_) {
      float ig = gl[tid], fg = gl[tid + H_], gg = gl[tid + 2*H_], og = gl[tid + 3*H_];
      creg = sigf(fg) * creg + sigf(ig) * tanhf_(gg);
      hreg = sigf(og) * tanhf_(creg);
      ((half_t*)hs)[tid] = (half_t)hreg;
    }
    __syncthreads();
  }

  // epilogue projection: recon[511] = proj(h_512)
  if (part == 1 && j < I_) {
    float a0 = 0.f, a1 = 0.f, a2 = 0.f, a3 = 0.f;
    const U8* hv = (const U8*)hs;
#pragma unroll
    for (int c = 0; c < 16; ++c) {
      U8 v = hv[c];
      a0 = fdot2(wv[4*c+0], v.h2[0], a0);
      a1 = fdot2(wv[4*c+1], v.h2[1], a1);
      a2 = fdot2(wv[4*c+2], v.h2[2], a2);
      a3 = fdot2(wv[4*c+3], v.h2[3], a3);
    }
    float r = bj + (a0 + a1) + (a2 + a3);
    rr[511 * I_ + j] = r;
    float d = r - mr[511 * I_ + j];
    rl += d * d;
  }

  // block reduction of squared error
  float v = rl;
#pragma unroll
  for (int off = 32; off > 0; off >>= 1) v += __shfl_down(v, off, 64);
  if ((tid & 63) == 0) red[tid >> 6] = v;
  __syncthreads();
  if (tid == 0) {
    float s = 0.f;
#pragma unroll
    for (int w = 0; w < 16; ++w) s += red[w];
    atomicAdd(&accums[0], s);
  }
}

__global__ void init_kernel(float* accums) {
  if (threadIdx.x < 2) accums[threadIdx.x] = 0.f;
}

__global__ void fin_kernel(const float* __restrict__ accums, float* __restrict__ dout) {
  if (threadIdx.x == 0) {
    float rec = accums[0] / (float)((size_t)B_ * T_ * I_);
    float kl = -0.5f * accums[1];
    dout[(size_t)B_*T_*I_ + 2 * B_ * L_] = rec + kl;
  }
}

extern "C" void kernel_launch(void* const* d_in, const int* in_sizes, int n_in,
                              void* d_out, int out_size, void* d_ws, size_t ws_size,
                              hipStream_t stream) {
  const float* motion = (const float*)d_in[0];
  const float* eps    = (const float*)d_in[1];
  const float* eWih   = (const float*)d_in[2];
  const float* eWhh   = (const float*)d_in[3];
  const float* eb     = (const float*)d_in[4];
  const float* muW    = (const float*)d_in[5];
  const float* mub    = (const float*)d_in[6];
  const float* varW   = (const float*)d_in[7];
  const float* varb   = (const float*)d_in[8];
  const float* fcW    = (const float*)d_in[9];
  const float* fcb    = (const float*)d_in[10];
  const float* dWih   = (const float*)d_in[11];
  const float* dWhh   = (const float*)d_in[12];
  const float* db     = (const float*)d_in[13];
  const float* oW     = (const float*)d_in[14];
  const float* obv    = (const float*)d_in[15];
  float* out = (float*)d_out;
  float* accums = (float*)d_ws;        // [0]=rec sum, [1]=kl raw sum
  float* dh0    = (float*)d_ws + 16;   // 256*128 f32

  hipLaunchKernelGGL(init_kernel, dim3(1), dim3(64), 0, stream, accums);
  hipLaunchKernelGGL(enc_kernel, dim3(B_), dim3(1024), 0, stream,
                     motion, eps, eWih, eWhh, eb, muW, mub, varW, varb, fcW, fcb,
                     out, dh0, accums);
  hipLaunchKernelGGL(dec_kernel, dim3(B_), dim3(1024), 0, stream,
                     motion, dWih, dWhh, db, oW, obv, dh0, out, accums);
  hipLaunchKernelGGL(fin_kernel, dim3(1), dim3(64), 0, stream, accums, out);
}